// Round 5
// baseline (542.046 us; speedup 1.0000x reference)
//
#include <hip/hip_runtime.h>

#define NT    8192
#define NP    8200
#define NPP   8320          // 65 * 128 = 260 * 32
#define NB    64
#define DV    64
#define NL    4
#define KSB   65            // one 128-t subtile per k_inv block
#define KSV   13            // k-split for v-DFT
#define PI2   6.28318530717958647692f

typedef _Float16 half8 __attribute__((ext_vector_type(8)));
typedef _Float16 half4 __attribute__((ext_vector_type(4)));
typedef float    f32x4 __attribute__((ext_vector_type(4)));

// ---------------- workspace layout (bytes) ----------------
// xT    : [NB][NPP][DV] f16                      68,157,440
// tabF  : [260][8][64][8] f16                     2,129,920
// tabI  : [4][520][64][8] f16 (alpha folded)      2,129,920
// Wfrag : [NL][2 hilo][2 ks][4 mf][64][8] f16       131,072
// zfrag : [NB][4][4][64][8] f16                   1,048,576
// xpart : [KSB][NB][DV][128] f16                 68,157,440
// Vpart : [KSV][NB][128] f16                        212,992
// G     : [128] f32                                     512
static const size_t B_XT   = 0;
static const size_t B_TABF = 68157440ull;
static const size_t B_TABI = B_TABF + 2129920ull;
static const size_t B_WFR  = B_TABI + 2129920ull;
static const size_t B_ZFR  = B_WFR  + 131072ull;
static const size_t B_XP   = B_ZFR  + 1048576ull;
static const size_t B_VP   = B_XP   + 68157440ull;
static const size_t B_G    = B_VP   + 212992ull;

// ---------------- trig tables in MFMA fragment order ----------------
__global__ void k_prep(_Float16* __restrict__ tabF, _Float16* __restrict__ tabI) {
    int idx = blockIdx.x * 256 + threadIdx.x;
    if (idx >= NPP * 64) return;
    int t = idx >> 6, k = idx & 63;
    float c = 0.f, s = 0.f;
    if (t < NP) {
        int m = (int)(((long long)t * (long long)k) % NP);
        float th = (float)m * (PI2 / (float)NP);
        sincosf(th, &s, &c);
    }
    float al = (k == 0) ? (1.f / NP) : (2.f / NP);
    // tabF: B[k-dim=t][col=m]: step=t>>5, cf=m>>4, lane=(m&15)+16*((t>>3)&3), j=t&7
    {
        int gs = t >> 5, lh = (t >> 3) & 3, j = t & 7, cf = k >> 3;
        int m0 = 2 * k, m1 = 2 * k + 1;
        tabF[(((size_t)gs * 8 + cf) * 64 + (m0 & 15) + 16 * lh) * 8 + j] = (_Float16)c;
        tabF[(((size_t)gs * 8 + cf) * 64 + (m1 & 15) + 16 * lh) * 8 + j] = (_Float16)s;
    }
    // tabI: B[k-dim=m][col=t]: ks=m>>5, tf=t>>4, lane=(t&15)+16*((m>>3)&3), j=m&7
    {
        int tf = t >> 4, lt = t & 15;
        int m0 = 2 * k, m1 = 2 * k + 1;
        tabI[(((size_t)(m0 >> 5) * 520 + tf) * 64 + lt + 16 * ((m0 >> 3) & 3)) * 8 + (m0 & 7)] = (_Float16)(al * c);
        tabI[(((size_t)(m1 >> 5) * 520 + tf) * 64 + lt + 16 * ((m1 >> 3) & 3)) * 8 + (m1 & 7)] = (_Float16)(al * s);
    }
}

// ---------------- w_w hi/lo f16 in A-frag order ----------------
__global__ void k_prep_w(const float* __restrict__ ww, _Float16* __restrict__ Wfrag) {
    int idx = blockIdx.x * 256 + threadIdx.x;
    if (idx >= NL * DV * DV) return;
    int l = idx >> 12, cd = idx & 4095, c = cd >> 6, d = cd & 63;
    float wv = ww[((size_t)l * DV + c) * DV + d];     // A[row=d][k=c]
    _Float16 h = (_Float16)wv;
    _Float16 lo = (_Float16)(wv - (float)h);
    int ks = c >> 5, mf = d >> 4;
    int lane = (d & 15) + 16 * ((c >> 3) & 3), j = c & 7;
    Wfrag[((((size_t)l * 2 + 0) * 2 + ks) * 4 + mf) * 512 + (size_t)lane * 8 + j] = h;
    Wfrag[((((size_t)l * 2 + 1) * 2 + ks) * 4 + mf) * 512 + (size_t)lane * 8 + j] = lo;
}

// ---------------- G[m] = DFT(grid) ----------------
__global__ void k_gd(const float* __restrict__ grd, float* __restrict__ G) {
    __shared__ float rb[256];
    int m = blockIdx.x, k = m >> 1, comp = m & 1;
    int tid = threadIdx.x;
    float s = 0.f;
    for (int t = tid; t < NT; t += 256) {
        int mm = (int)(((long long)t * (long long)k) % NP);
        float th = (float)mm * (PI2 / (float)NP);
        float sn, cs; sincosf(th, &sn, &cs);
        s += grd[t] * (comp ? sn : cs);
    }
    rb[tid] = s; __syncthreads();
    for (int h = 128; h > 0; h >>= 1) { if (tid < h) rb[tid] += rb[tid + h]; __syncthreads(); }
    if (tid == 0) G[m] = rb[0];
}

// ---------------- initial projection -> xT[b][t][c] f16 ----------------
__global__ void k_proj(const float* __restrict__ v, const float* __restrict__ grd,
                       const float* __restrict__ pw, const float* __restrict__ pb,
                       _Float16* __restrict__ xT) {
    int b = blockIdx.y;
    int t = blockIdx.x * 128 + (threadIdx.x >> 1);
    int hf = threadIdx.x & 1;
    bool in = (t < NT);
    float vv = in ? v[(size_t)b * NT + t] : 0.f;
    float gg = in ? grd[t] : 0.f;
    _Float16 buf[32];
    #pragma unroll
    for (int q = 0; q < 32; ++q) {
        int c = hf * 32 + q;
        float val = in ? fmaf(vv, pw[c], fmaf(gg, pw[64 + c], pb[c])) : 0.f;
        buf[q] = (_Float16)val;
    }
    #pragma unroll
    for (int q = 0; q < 4; ++q)
        *(half8*)&xT[((size_t)b * NPP + t) * 64 + hf * 32 + q * 8] = *(half8*)&buf[q * 8];
}

// ---------------- partial DFT of v (A rows = batch) ----------------
__launch_bounds__(256)
__global__ void k_fdft_v(const float* __restrict__ v, const _Float16* __restrict__ tabF,
                         _Float16* __restrict__ Vp) {
    int ksb = blockIdx.x;
    int tid = threadIdx.x, w = tid >> 6, lane = tid & 63, g = lane >> 4, r = lane & 15;
    const half8* tFv = (const half8*)tabF;
    f32x4 acc[4][2];
    #pragma unroll
    for (int mf = 0; mf < 4; ++mf)
        #pragma unroll
        for (int nf = 0; nf < 2; ++nf) acc[mf][nf] = (f32x4){0.f, 0.f, 0.f, 0.f};
    for (int s = 0; s < 20; ++s) {
        int gs = ksb * 20 + s;
        int t0 = gs * 32 + g * 8;
        half8 a[4];
        #pragma unroll
        for (int mf = 0; mf < 4; ++mf) {
            int brow = mf * 16 + r;
            half8 hv;
            if (t0 < NT) {
                const float4* pv = (const float4*)&v[(size_t)brow * NT + t0];
                float4 v0 = pv[0], v1 = pv[1];
                hv[0] = (_Float16)v0.x; hv[1] = (_Float16)v0.y; hv[2] = (_Float16)v0.z; hv[3] = (_Float16)v0.w;
                hv[4] = (_Float16)v1.x; hv[5] = (_Float16)v1.y; hv[6] = (_Float16)v1.z; hv[7] = (_Float16)v1.w;
            } else {
                #pragma unroll
                for (int j = 0; j < 8; ++j) hv[j] = (_Float16)0.f;
            }
            a[mf] = hv;
        }
        half8 bb[2];
        #pragma unroll
        for (int nf = 0; nf < 2; ++nf) bb[nf] = tFv[((size_t)gs * 8 + w * 2 + nf) * 64 + lane];
        #pragma unroll
        for (int mf = 0; mf < 4; ++mf)
            #pragma unroll
            for (int nf = 0; nf < 2; ++nf)
                acc[mf][nf] = __builtin_amdgcn_mfma_f32_16x16x32_f16(a[mf], bb[nf], acc[mf][nf], 0, 0, 0);
    }
    #pragma unroll
    for (int mf = 0; mf < 4; ++mf)
        #pragma unroll
        for (int nf = 0; nf < 2; ++nf)
            #pragma unroll
            for (int reg = 0; reg < 4; ++reg) {
                int brow = mf * 16 + g * 4 + reg;
                int m = w * 32 + nf * 16 + r;
                Vp[((size_t)ksb * NB + brow) * 128 + m] = (_Float16)acc[mf][nf][reg];
            }
}

// ---------------- spectral mix layer 0 (rank-2 X build) ----------------
__launch_bounds__(256)
__global__ void k_spec0(const _Float16* __restrict__ Vp, const float* __restrict__ G,
                        const float* __restrict__ pw, const float* __restrict__ pb,
                        const float* __restrict__ fw_l, _Float16* __restrict__ zfr) {
    __shared__ float Xs[64][32];
    __shared__ float Vs[32], Gs[32];
    int b = blockIdx.y, kq = blockIdx.x, tid = threadIdx.x;
    if (tid < 32) {
        int m = kq * 32 + tid;
        float ssum = 0.f;
        #pragma unroll
        for (int ks = 0; ks < KSV; ++ks) ssum += (float)Vp[((size_t)ks * NB + b) * 128 + m];
        Vs[tid] = ssum;
        Gs[tid] = G[m];
    }
    __syncthreads();
    #pragma unroll
    for (int q = 0; q < 8; ++q) {
        int flat = q * 256 + tid;
        int i = flat >> 5, ml = flat & 31;
        float xv = pw[i] * Vs[ml] + pw[64 + i] * Gs[ml];
        if (kq == 0 && ml == 0) xv += pb[i] * (float)NT;
        Xs[i][ml] = xv;
    }
    __syncthreads();
    #pragma unroll
    for (int q = 0; q < 4; ++q) {
        int flat = q * 256 + tid;
        int o = flat >> 4, kl = flat & 15;
        int k = kq * 16 + kl;
        float yr = 0.f, yi = 0.f;
        #pragma unroll 8
        for (int i = 0; i < 64; ++i) {
            float2 xv = *(const float2*)&Xs[i][2 * kl];
            float2 wv = *(const float2*)&fw_l[(((size_t)i * DV + o) * 64 + k) * 2];
            yr = fmaf(xv.x, wv.x, fmaf(xv.y, wv.y, yr));
            yi = fmaf(xv.x, wv.y, fmaf(-xv.y, wv.x, yi));
        }
        int mf = o >> 4, mm = 2 * kl, m1 = mm + 1;
        zfr[((((size_t)b * 4 + kq) * 4 + mf) * 64 + (o & 15) + 16 * (mm >> 3)) * 8 + (mm & 7)] = (_Float16)yr;
        zfr[((((size_t)b * 4 + kq) * 4 + mf) * 64 + (o & 15) + 16 * (m1 >> 3)) * 8 + (m1 & 7)] = (_Float16)(-yi);
    }
}

// ---------------- spectral mix layers 1..3 (reduce 65 partials) ----------------
__launch_bounds__(256)
__global__ void k_spec(const _Float16* __restrict__ xpart, const float* __restrict__ fw_l,
                       _Float16* __restrict__ zfr) {
    __shared__ float Xs[64][32];
    int b = blockIdx.y, kq = blockIdx.x, tid = threadIdx.x;
    #pragma unroll
    for (int q = 0; q < 8; ++q) {
        int flat = q * 256 + tid;
        int i = flat >> 5, ml = flat & 31;
        float ssum = 0.f;
        #pragma unroll 5
        for (int ks = 0; ks < KSB; ++ks)
            ssum += (float)xpart[(((size_t)ks * NB + b) * DV + i) * 128 + kq * 32 + ml];
        Xs[i][ml] = ssum;
    }
    __syncthreads();
    #pragma unroll
    for (int q = 0; q < 4; ++q) {
        int flat = q * 256 + tid;
        int o = flat >> 4, kl = flat & 15;
        int k = kq * 16 + kl;
        float yr = 0.f, yi = 0.f;
        #pragma unroll 8
        for (int i = 0; i < 64; ++i) {
            float2 xv = *(const float2*)&Xs[i][2 * kl];
            float2 wv = *(const float2*)&fw_l[(((size_t)i * DV + o) * 64 + k) * 2];
            yr = fmaf(xv.x, wv.x, fmaf(xv.y, wv.y, yr));
            yi = fmaf(xv.x, wv.y, fmaf(-xv.y, wv.x, yi));
        }
        int mf = o >> 4, mm = 2 * kl, m1 = mm + 1;
        zfr[((((size_t)b * 4 + kq) * 4 + mf) * 64 + (o & 15) + 16 * (mm >> 3)) * 8 + (mm & 7)] = (_Float16)yr;
        zfr[((((size_t)b * 4 + kq) * 4 + mf) * 64 + (o & 15) + 16 * (m1 >> 3)) * 8 + (m1 & 7)] = (_Float16)(-yi);
    }
}

// ---------------- fused: inverse DFT + local + bias + relu + fwd DFT (1 subtile/block) ----------------
template <bool LAST>
__launch_bounds__(256)
__global__ void k_inv(const _Float16* __restrict__ zfr, const _Float16* __restrict__ tabI,
                      const _Float16* __restrict__ tabF, const _Float16* __restrict__ Wl,
                      const float* __restrict__ wb_l, const float* __restrict__ qw,
                      const float* __restrict__ qb, _Float16* __restrict__ xT,
                      _Float16* __restrict__ xpart, float* __restrict__ out) {
    __shared__ _Float16 xls[64 * 128];    // [c][t-swizzled] 16 KiB
    __shared__ float red[4][2][64];
    int b = blockIdx.y, ksb = blockIdx.x;
    int tid = threadIdx.x, w = tid >> 6, lane = tid & 63;
    int g = lane >> 4, r = lane & 15;
    int tw = ksb * 128 + w * 32;
    const half8* zfv = (const half8*)zfr;
    const half8* tIv = (const half8*)tabI;
    const half8* tFv = (const half8*)tabF;
    const half8* wfv = (const half8*)Wl;

    // ---- old-x B-frags (direct coalesced global, this wave's own 32-t slice) ----
    half8 xb[2][2];
    #pragma unroll
    for (int ks = 0; ks < 2; ++ks)
        #pragma unroll
        for (int nf = 0; nf < 2; ++nf)
            xb[ks][nf] = *(const half8*)&xT[((size_t)b * NPP + tw + nf * 16 + r) * 64 + ks * 32 + g * 8];

    f32x4 acc[4][2];
    #pragma unroll
    for (int mf = 0; mf < 4; ++mf)
        #pragma unroll
        for (int nf = 0; nf < 2; ++nf) acc[mf][nf] = (f32x4){0.f, 0.f, 0.f, 0.f};

    // ---- spectral: A=z, B=tabI ----
    #pragma unroll
    for (int ks4 = 0; ks4 < 4; ++ks4) {
        half8 az[4], bt[2];
        #pragma unroll
        for (int mf = 0; mf < 4; ++mf)
            az[mf] = zfv[(((size_t)b * 4 + ks4) * 4 + mf) * 64 + lane];
        #pragma unroll
        for (int nf = 0; nf < 2; ++nf)
            bt[nf] = tIv[((size_t)ks4 * 520 + (tw >> 4) + nf) * 64 + lane];
        #pragma unroll
        for (int mf = 0; mf < 4; ++mf)
            #pragma unroll
            for (int nf = 0; nf < 2; ++nf)
                acc[mf][nf] = __builtin_amdgcn_mfma_f32_16x16x32_f16(az[mf], bt[nf], acc[mf][nf], 0, 0, 0);
    }
    // ---- local: (Whi + Wlo) * x ----
    #pragma unroll
    for (int hl = 0; hl < 2; ++hl)
        #pragma unroll
        for (int ks = 0; ks < 2; ++ks) {
            half8 aw[4];
            #pragma unroll
            for (int mf = 0; mf < 4; ++mf)
                aw[mf] = wfv[((size_t)(hl * 2 + ks) * 4 + mf) * 64 + lane];
            #pragma unroll
            for (int mf = 0; mf < 4; ++mf)
                #pragma unroll
                for (int nf = 0; nf < 2; ++nf)
                    acc[mf][nf] = __builtin_amdgcn_mfma_f32_16x16x32_f16(aw[mf], xb[ks][nf], acc[mf][nf], 0, 0, 0);
        }

    if (!LAST) {
        // ---- epilogue: bias + relu, store xT + LDS (swizzled [c][t]) ----
        #pragma unroll
        for (int mf = 0; mf < 4; ++mf)
            #pragma unroll
            for (int nf = 0; nf < 2; ++nf) {
                int t = tw + nf * 16 + r;
                int tl = w * 32 + nf * 16 + r;
                half4 h4;
                #pragma unroll
                for (int reg = 0; reg < 4; ++reg) {
                    int o = mf * 16 + g * 4 + reg;
                    float val = fmaxf(acc[mf][nf][reg] + wb_l[o], 0.f);
                    h4[reg] = (_Float16)val;
                }
                *(half4*)&xT[((size_t)b * NPP + t) * 64 + mf * 16 + g * 4] = h4;
                #pragma unroll
                for (int reg = 0; reg < 4; ++reg) {
                    int c = mf * 16 + g * 4 + reg;
                    xls[(c << 7) + ((((tl << 1) ^ ((c & 15) << 4))) >> 1)] = h4[reg];
                }
            }
        __syncthreads();
        // ---- fwd DFT of new x: A from LDS, B=tabF ----
        f32x4 dacc[4][2];
        #pragma unroll
        for (int cf = 0; cf < 4; ++cf)
            #pragma unroll
            for (int nf2 = 0; nf2 < 2; ++nf2) dacc[cf][nf2] = (f32x4){0.f, 0.f, 0.f, 0.f};
        #pragma unroll
        for (int ks = 0; ks < 4; ++ks) {
            half8 ax[4], bf2[2];
            #pragma unroll
            for (int cf = 0; cf < 4; ++cf) {
                int c = cf * 16 + r;
                int off = (ks * 64 + g * 16) ^ ((c & 15) << 4);
                ax[cf] = *(const half8*)&xls[(c << 7) + (off >> 1)];
            }
            int gs = ksb * 4 + ks;
            #pragma unroll
            for (int nf2 = 0; nf2 < 2; ++nf2)
                bf2[nf2] = tFv[((size_t)gs * 8 + w * 2 + nf2) * 64 + lane];
            #pragma unroll
            for (int cf = 0; cf < 4; ++cf)
                #pragma unroll
                for (int nf2 = 0; nf2 < 2; ++nf2)
                    dacc[cf][nf2] = __builtin_amdgcn_mfma_f32_16x16x32_f16(ax[cf], bf2[nf2], dacc[cf][nf2], 0, 0, 0);
        }
        #pragma unroll
        for (int cf = 0; cf < 4; ++cf)
            #pragma unroll
            for (int nf2 = 0; nf2 < 2; ++nf2)
                #pragma unroll
                for (int reg = 0; reg < 4; ++reg) {
                    int c = cf * 16 + g * 4 + reg;
                    int m = w * 32 + nf2 * 16 + r;
                    xpart[(((size_t)ksb * NB + b) * DV + c) * 128 + m] = (_Float16)dacc[cf][nf2][reg];
                }
    } else {
        float p0 = 0.f, p1 = 0.f;
        #pragma unroll
        for (int mf = 0; mf < 4; ++mf)
            #pragma unroll
            for (int reg = 0; reg < 4; ++reg) {
                int o = mf * 16 + g * 4 + reg;
                float qq = qw[o], bias = wb_l[o];
                p0 = fmaf(acc[mf][0][reg] + bias, qq, p0);
                p1 = fmaf(acc[mf][1][reg] + bias, qq, p1);
            }
        red[w][0][lane] = p0;
        red[w][1][lane] = p1;
        __syncthreads();
        if (tid < 128) {
            int w2 = tid >> 5, nf2 = (tid >> 4) & 1, c2 = tid & 15;
            float s2 = 0.f;
            #pragma unroll
            for (int g2 = 0; g2 < 4; ++g2) s2 += red[w2][nf2][g2 * 16 + c2];
            int t = ksb * 128 + w2 * 32 + nf2 * 16 + c2;
            if (t < NT) out[(size_t)b * NT + t] = s2 + qb[0];
        }
    }
}

extern "C" void kernel_launch(void* const* d_in, const int* in_sizes, int n_in,
                              void* d_out, int out_size, void* d_ws, size_t ws_size,
                              hipStream_t stream) {
    const float* v   = (const float*)d_in[0];
    const float* grd = (const float*)d_in[1];
    const float* pw  = (const float*)d_in[2];
    const float* pb  = (const float*)d_in[3];
    const float* fw  = (const float*)d_in[4];
    const float* ww  = (const float*)d_in[5];
    const float* wb  = (const float*)d_in[6];
    const float* qw  = (const float*)d_in[7];
    const float* qb  = (const float*)d_in[8];
    float* out = (float*)d_out;

    char* wsb = (char*)d_ws;
    _Float16* xT    = (_Float16*)(wsb + B_XT);
    _Float16* tabFb = (_Float16*)(wsb + B_TABF);
    _Float16* tabIb = (_Float16*)(wsb + B_TABI);
    _Float16* Wfrag = (_Float16*)(wsb + B_WFR);
    _Float16* zfrag = (_Float16*)(wsb + B_ZFR);
    _Float16* xpart = (_Float16*)(wsb + B_XP);
    _Float16* Vpart = (_Float16*)(wsb + B_VP);
    float*    G     = (float*)(wsb + B_G);

    k_prep<<<(NPP * 64 + 255) / 256, 256, 0, stream>>>(tabFb, tabIb);
    k_prep_w<<<(NL * DV * DV + 255) / 256, 256, 0, stream>>>(ww, Wfrag);
    k_gd<<<128, 256, 0, stream>>>(grd, G);
    k_proj<<<dim3(65, NB), 256, 0, stream>>>(v, grd, pw, pb, xT);
    k_fdft_v<<<KSV, 256, 0, stream>>>(v, tabFb, Vpart);

    for (int l = 0; l < NL; ++l) {
        if (l == 0)
            k_spec0<<<dim3(4, NB), 256, 0, stream>>>(Vpart, G, pw, pb, fw, zfrag);
        else
            k_spec<<<dim3(4, NB), 256, 0, stream>>>(xpart, fw + (size_t)l * DV * DV * 64 * 2, zfrag);
        // per-layer Wfrag block = 2(hilo) * 2(ks) * 4(mf) * 64(lane) * 8(j) = 8192 f16
        const _Float16* wf_l = Wfrag + (size_t)l * 8192;
        const float* wb_l = wb + (size_t)l * DV;
        if (l < NL - 1)
            k_inv<false><<<dim3(KSB, NB), 256, 0, stream>>>(
                zfrag, tabIb, tabFb, wf_l, wb_l, qw, qb, xT, xpart, out);
        else
            k_inv<true><<<dim3(KSB - 1, NB), 256, 0, stream>>>(
                zfrag, tabIb, tabFb, wf_l, wb_l, qw, qb, xT, xpart, out);
    }
}